// Round 4
// baseline (1629.158 us; speedup 1.0000x reference)
//
#include <hip/hip_runtime.h>
#include <stdint.h>

// Problem sizes (fixed by the reference)
#define NQn 131072
#define NCn 65536
#define En  1048576
// D = 128, HID = 256

typedef __bf16 bf16;
typedef __bf16 bf16x2 __attribute__((ext_vector_type(2)));
typedef __bf16 bf16x4 __attribute__((ext_vector_type(4)));
typedef __bf16 bf16x8 __attribute__((ext_vector_type(8)));
typedef float  f32x4  __attribute__((ext_vector_type(4)));

// ---------------------------------------------------------------------------
// Weight transpose + bf16 cast: Wt[m*K+k] = bf16(W[k*M+m])
// ---------------------------------------------------------------------------
__global__ void wtrans_all(
    const float* __restrict__ w0, bf16* __restrict__ t0,
    const float* __restrict__ w1, bf16* __restrict__ t1,
    const float* __restrict__ w2, bf16* __restrict__ t2,
    const float* __restrict__ w3, bf16* __restrict__ t3,
    const float* __restrict__ w4, bf16* __restrict__ t4,
    const float* __restrict__ w5, bf16* __restrict__ t5,
    const float* __restrict__ w6, bf16* __restrict__ t6,
    const float* __restrict__ w7, bf16* __restrict__ t7) {
  const float* W; bf16* T; int K, M;
  switch (blockIdx.y) {
    case 0: W = w0; T = t0; K = 128; M = 128; break;  // Wres_Q
    case 1: W = w1; T = t1; K = 128; M = 128; break;  // Wres_C
    case 2: W = w2; T = t2; K = 128; M = 128; break;  // Wrel_QC
    case 3: W = w3; T = t3; K = 128; M = 128; break;  // Wrel_CQ
    case 4: W = w4; T = t4; K = 256; M = 256; break;  // W1_Q
    case 5: W = w5; T = t5; K = 256; M = 256; break;  // W1_C
    case 6: W = w6; T = t6; K = 256; M = 128; break;  // W2_Q
    default: W = w7; T = t7; K = 256; M = 128; break; // W2_C
  }
  int t = blockIdx.x * 256 + threadIdx.x;
  if (t >= K * M) return;
  int m = t % M, k = t / M;
  T[m * K + k] = (bf16)W[k * M + m];
}

// ---------------------------------------------------------------------------
// Generic 128x128-tile bf16 MFMA GEMM.
// ASRC: 0 bf16 input; 1 f32 input (cast); 2 f32 input + fused LayerNorm
//       (NK must be 1, row = one K-tile; per-row stats via half-wave shfl).
// EPI:  0 store bf16; 1 row-scale store bf16; 2 +bias tanh-GELU store bf16;
//       3 +bias +resid store f32.
// LDS XOR-swizzled both sides.
// ---------------------------------------------------------------------------
#define ASRC_BF16 0
#define ASRC_F32  1
#define ASRC_LN   2
#define EPI_BF16  0
#define EPI_RSCL  1
#define EPI_GELU  2
#define EPI_RES   3

template <int ASRC, int EPI, int NK>
__global__ __launch_bounds__(256, 2) void gemm_kernel(
    const void* __restrict__ A0, const void* __restrict__ A1,
    const bf16* __restrict__ Bt, const float* __restrict__ bias,
    const float* __restrict__ rowscale, const bf16* __restrict__ resid,
    const float* __restrict__ lng, const float* __restrict__ lnbp,
    bf16* __restrict__ outB, float* __restrict__ outF,
    int ldA, int kOff, int ldOut) {
  __shared__ __align__(16) unsigned char lds[65536];
  const int tid = threadIdx.x;
  const int row0 = blockIdx.x * 128;
  const int col0 = blockIdx.y * 128;
  const int wid = tid >> 6, lane = tid & 63;
  const int wrow = (wid >> 1) * 64, wcol = (wid & 1) * 64;

  f32x4 acc[4][4] = {};

  #pragma unroll
  for (int kc = 0; kc < NK; ++kc) {
    if (kc) __syncthreads();
    const void* ap = (kc == 0) ? A0 : A1;
    const int kofs = kc * kOff;
    if (ASRC == ASRC_F32) {
      const float* Af = (const float*)ap;
      #pragma unroll
      for (int it = 0; it < 16; ++it) {
        int lin = it * 256 + tid;
        int r = lin >> 5;
        int c = (lin & 31) * 4;
        float4 v = *(const float4*)(Af + (size_t)(row0 + r) * ldA + kofs + c);
        bf16x4 w;
        w[0] = (bf16)v.x; w[1] = (bf16)v.y; w[2] = (bf16)v.z; w[3] = (bf16)v.w;
        *(bf16x4*)(lds + r * 256 + ((c * 2) ^ ((r & 7) << 4))) = w;
      }
    } else if (ASRC == ASRC_LN) {
      const float* Af = (const float*)ap;
      #pragma unroll
      for (int it = 0; it < 16; ++it) {
        int lin = it * 256 + tid;
        int r = lin >> 5;
        int c = (lin & 31) * 4;
        float4 v = *(const float4*)(Af + (size_t)(row0 + r) * 128 + c);
        // row stats across the 32 consecutive tids holding this row
        float s = v.x + v.y + v.z + v.w;
        #pragma unroll
        for (int o = 16; o; o >>= 1) s += __shfl_xor(s, o, 64);
        float mean = s * (1.0f / 128.0f);
        float d0 = v.x - mean, d1 = v.y - mean, d2 = v.z - mean, d3 = v.w - mean;
        float q = d0 * d0 + d1 * d1 + d2 * d2 + d3 * d3;
        #pragma unroll
        for (int o = 16; o; o >>= 1) q += __shfl_xor(q, o, 64);
        float rsv = rsqrtf(q * (1.0f / 128.0f) + 1e-5f);
        float4 gg = *(const float4*)(lng + c);
        float4 bb = *(const float4*)(lnbp + c);
        bf16x4 w;
        w[0] = (bf16)(d0 * rsv * gg.x + bb.x);
        w[1] = (bf16)(d1 * rsv * gg.y + bb.y);
        w[2] = (bf16)(d2 * rsv * gg.z + bb.z);
        w[3] = (bf16)(d3 * rsv * gg.w + bb.w);
        *(bf16x4*)(lds + r * 256 + ((c * 2) ^ ((r & 7) << 4))) = w;
      }
    } else {
      const bf16* Ab = (const bf16*)ap;
      #pragma unroll
      for (int it = 0; it < 8; ++it) {
        int lin = it * 256 + tid;
        int r = lin >> 4;
        int cb = (lin & 15) * 16;
        bf16x8 v = *(const bf16x8*)((const char*)Ab +
                    ((size_t)(row0 + r) * ldA + kofs) * 2 + cb);
        *(bf16x8*)(lds + r * 256 + (cb ^ ((r & 7) << 4))) = v;
      }
    }
    #pragma unroll
    for (int it = 0; it < 8; ++it) {
      int lin = it * 256 + tid;
      int r = lin >> 4;
      int cb = (lin & 15) * 16;
      bf16x8 v = *(const bf16x8*)((const char*)Bt +
                  ((size_t)(col0 + r) * (NK * 128) + kc * 128) * 2 + cb);
      *(bf16x8*)(lds + 32768 + r * 256 + (cb ^ ((r & 7) << 4))) = v;
    }
    __syncthreads();
    #pragma unroll
    for (int kk = 0; kk < 4; ++kk) {
      bf16x8 af[4], bfv[4];
      const int kb = kk * 64 + (lane >> 4) * 16;
      #pragma unroll
      for (int fr = 0; fr < 4; ++fr) {
        int ar = wrow + fr * 16 + (lane & 15);
        af[fr] = *(const bf16x8*)(lds + ar * 256 + (kb ^ ((ar & 7) << 4)));
      }
      #pragma unroll
      for (int fc = 0; fc < 4; ++fc) {
        int br = wcol + fc * 16 + (lane & 15);
        bfv[fc] = *(const bf16x8*)(lds + 32768 + br * 256 + (kb ^ ((br & 7) << 4)));
      }
      #pragma unroll
      for (int fr = 0; fr < 4; ++fr)
        #pragma unroll
        for (int fc = 0; fc < 4; ++fc)
          acc[fr][fc] = __builtin_amdgcn_mfma_f32_16x16x32_bf16(
              af[fr], bfv[fc], acc[fr][fc], 0, 0, 0);
    }
  }

  const int rbase = row0 + wrow + (lane >> 4) * 4;
  const int cbase = col0 + wcol + (lane & 15);
  #pragma unroll
  for (int fr = 0; fr < 4; ++fr) {
    float rs[4];
    if (EPI == EPI_RSCL) {
      #pragma unroll
      for (int r = 0; r < 4; ++r) {
        float dv = rowscale[rbase + fr * 16 + r];
        rs[r] = dv > 0.f ? rsqrtf(dv) : 0.f;
      }
    }
    #pragma unroll
    for (int fc = 0; fc < 4; ++fc) {
      const int col = cbase + fc * 16;
      float bv = (EPI == EPI_GELU || EPI == EPI_RES) ? bias[col] : 0.f;
      #pragma unroll
      for (int r = 0; r < 4; ++r) {
        const int row = rbase + fr * 16 + r;
        float x = acc[fr][fc][r];
        if (EPI == EPI_BF16) {
          outB[(size_t)row * ldOut + col] = (bf16)x;
        } else if (EPI == EPI_RSCL) {
          outB[(size_t)row * ldOut + col] = (bf16)(x * rs[r]);
        } else if (EPI == EPI_GELU) {
          x += bv;
          // tanh-form GELU; tanh(u) = 1 - 2/(exp(2u)+1)
          float u2 = 1.5957691216057308f * (x + 0.044715f * x * x * x);
          float e = __expf(u2);
          float th = 1.f - 2.f / (e + 1.f);
          x = 0.5f * x * (1.f + th);
          outB[(size_t)row * ldOut + col] = (bf16)x;
        } else {
          x += bv + (float)resid[(size_t)row * 128 + col];
          outF[(size_t)row * 128 + col] = x;
        }
      }
    }
  }
}

// ---------------------------------------------------------------------------
// Bucket histogram from deg (bucket = 128 dst rows). One wave per bucket.
// bcnt layout: [512 QC][1024 CQ]
// ---------------------------------------------------------------------------
__global__ __launch_bounds__(256) void bucket_hist(
    const float* __restrict__ degQC, const float* __restrict__ degCQ,
    int* __restrict__ bcnt) {
  int w = (blockIdx.x * 256 + threadIdx.x) >> 6;
  int lane = threadIdx.x & 63;
  const float* deg = (w < 512) ? (degQC + (size_t)w * 128)
                               : (degCQ + (size_t)(w - 512) * 128);
  float s = deg[lane] + deg[lane + 64];
  #pragma unroll
  for (int o = 32; o; o >>= 1) s += __shfl_xor(s, o, 64);
  if (lane == 0) bcnt[w] = (int)(s + 0.5f);
}

// Single-block exclusive scan over both bucket-count arrays -> bases + cursors.
__global__ __launch_bounds__(1024) void bucket_scan(
    const int* __restrict__ bcnt,
    int* __restrict__ baseQC, int* __restrict__ gcurQC,
    int* __restrict__ baseCQ, int* __restrict__ gcurCQ) {
  __shared__ int ss[1024];
  const int t = threadIdx.x;
  // QC (512 buckets)
  int v = (t < 512) ? bcnt[t] : 0;
  ss[t] = v;
  __syncthreads();
  for (int o = 1; o < 1024; o <<= 1) {
    int x = (t >= o) ? ss[t - o] : 0;
    __syncthreads();
    ss[t] += x;
    __syncthreads();
  }
  if (t < 512) { int e = ss[t] - v; baseQC[t] = e; gcurQC[t] = e; }
  if (t == 0) baseQC[512] = En;
  __syncthreads();
  // CQ (1024 buckets)
  int v2 = bcnt[512 + t];
  ss[t] = v2;
  __syncthreads();
  for (int o = 1; o < 1024; o <<= 1) {
    int x = (t >= o) ? ss[t - o] : 0;
    __syncthreads();
    ss[t] += x;
    __syncthreads();
  }
  { int e = ss[t] - v2; baseCQ[t] = e; gcurCQ[t] = e; }
  if (t == 0) baseCQ[1024] = En;
}

// ---------------------------------------------------------------------------
// Pass A: partition (src,dst) pairs into bucket-grouped ebuf (bucket=dst>>7).
// ---------------------------------------------------------------------------
#define CHUNK 4096

template <int NB>
__global__ __launch_bounds__(256) void bucketA(
    const int* __restrict__ esrc, const int* __restrict__ edst,
    int* __restrict__ gcur, uint2* __restrict__ ebuf) {
  __shared__ int lcount[NB], lexcl[NB], lbase[NB], lofs[NB];
  __shared__ int ss[256];
  __shared__ uint2 stage[CHUNK];
  const int t = threadIdx.x;
  for (int b = t; b < NB; b += 256) lcount[b] = 0;
  __syncthreads();
  const int e0 = blockIdx.x * CHUNK;
  uint2 ed[16];
  #pragma unroll
  for (int j = 0; j < 16; ++j) {
    int e = e0 + j * 256 + t;
    ed[j].x = (unsigned)esrc[e];
    ed[j].y = (unsigned)edst[e];
    atomicAdd(&lcount[ed[j].y >> 7], 1);
  }
  __syncthreads();
  constexpr int R = NB / 256;
  int c[R]; int mysum = 0;
  #pragma unroll
  for (int j = 0; j < R; ++j) { c[j] = lcount[t * R + j]; mysum += c[j]; }
  ss[t] = mysum;
  __syncthreads();
  for (int o = 1; o < 256; o <<= 1) {
    int x = (t >= o) ? ss[t - o] : 0;
    __syncthreads();
    ss[t] += x;
    __syncthreads();
  }
  int run = ss[t] - mysum;
  #pragma unroll
  for (int j = 0; j < R; ++j) { lexcl[t * R + j] = run; run += c[j]; }
  __syncthreads();
  for (int b = t; b < NB; b += 256) {
    lbase[b] = atomicAdd(&gcur[b], lcount[b]);
    lofs[b]  = lexcl[b];
  }
  __syncthreads();
  #pragma unroll
  for (int j = 0; j < 16; ++j) {
    int b = ed[j].y >> 7;
    int p = atomicAdd(&lofs[b], 1);
    stage[p] = ed[j];
  }
  __syncthreads();
  for (int i = t; i < CHUNK; i += 256) {
    uint2 v = stage[i];
    int b = v.y >> 7;
    ebuf[lbase[b] + (i - lexcl[b])] = v;
  }
}

// ---------------------------------------------------------------------------
// Fused bucketB+gather: one block per 128-dst bucket; edge-parallel
// accumulation into LDS f32 via ds_add; scaled bf16 writeout.
// ---------------------------------------------------------------------------
__global__ __launch_bounds__(512) void bucket_gather(
    const uint2* __restrict__ ebuf, const int* __restrict__ bbase,
    const bf16* __restrict__ Xn, const float* __restrict__ degdst,
    const float* __restrict__ gate, bf16* __restrict__ msg) {
  __shared__ float acc[128][128];
  const int t = threadIdx.x;
  float4 z = {0.f, 0.f, 0.f, 0.f};
  #pragma unroll
  for (int i = 0; i < 8; ++i) ((float4*)acc)[i * 512 + t] = z;
  __syncthreads();
  const int b = blockIdx.x;
  const int lane = t & 63, wid = t >> 6;   // 8 waves
  const int base = bbase[b], end = bbase[b + 1];
  const int U = 8, STR = 8 * U;
  int i = base + wid * U;
  for (; i + U <= end; i += STR) {
    uint2 ed[U]; bf16x2 v[U];
    #pragma unroll
    for (int j = 0; j < U; ++j) ed[j] = ebuf[i + j];
    #pragma unroll
    for (int j = 0; j < U; ++j)
      v[j] = *(const bf16x2*)(Xn + (size_t)ed[j].x * 128 + lane * 2);
    #pragma unroll
    for (int j = 0; j < U; ++j) {
      float* p = &acc[ed[j].y & 127][lane * 2];
      atomicAdd(p, (float)v[j][0]);
      atomicAdd(p + 1, (float)v[j][1]);
    }
  }
  if (i < end) {  // only the wave owning the final partial chunk lands here
    int n = end - i;
    for (int j = 0; j < n; ++j) {
      uint2 e2 = ebuf[i + j];
      bf16x2 v0 = *(const bf16x2*)(Xn + (size_t)e2.x * 128 + lane * 2);
      float* p = &acc[e2.y & 127][lane * 2];
      atomicAdd(p, (float)v0[0]);
      atomicAdd(p + 1, (float)v0[1]);
    }
  }
  __syncthreads();
  const float gt = gate[0];
  const int d0 = b << 7;
  #pragma unroll
  for (int rr = 0; rr < 128; rr += 32) {
    int row = rr + (t >> 4);
    float dv = degdst[d0 + row];
    float sc = (dv > 0.f ? rsqrtf(dv) : 0.f) * gt;
    int c = (t & 15) * 8;
    bf16x8 o8;
    #pragma unroll
    for (int j = 0; j < 8; ++j) o8[j] = (bf16)(acc[row][c + j] * sc);
    *(bf16x8*)(msg + (size_t)(d0 + row) * 128 + c) = o8;
  }
}

// ---------------------------------------------------------------------------
extern "C" void kernel_launch(void* const* d_in, const int* in_sizes, int n_in,
                              void* d_out, int out_size, void* d_ws, size_t ws_size,
                              hipStream_t stream) {
  const float* H_Q        = (const float*)d_in[0];
  const float* H_C        = (const float*)d_in[1];
  const int*   eQC_src    = (const int*)d_in[2];
  const int*   eQC_dst    = (const int*)d_in[3];
  const int*   eCQ_src    = (const int*)d_in[4];
  const int*   eCQ_dst    = (const int*)d_in[5];
  const float* deg_QC_src = (const float*)d_in[6];
  const float* deg_QC_dst = (const float*)d_in[7];
  const float* deg_CQ_src = (const float*)d_in[8];
  const float* deg_CQ_dst = (const float*)d_in[9];
  const float* ln_g_Q     = (const float*)d_in[10];
  const float* ln_b_Q     = (const float*)d_in[11];
  const float* Wres_Q     = (const float*)d_in[12];
  const float* ln_g_C     = (const float*)d_in[13];
  const float* ln_b_C     = (const float*)d_in[14];
  const float* Wres_C     = (const float*)d_in[15];
  const float* Wrel_QC    = (const float*)d_in[16];
  const float* Wrel_CQ    = (const float*)d_in[17];
  const float* gate_QC    = (const float*)d_in[18];
  const float* gate_CQ    = (const float*)d_in[19];
  const float* W1_Q       = (const float*)d_in[20];
  const float* b1_Q       = (const float*)d_in[21];
  const float* W2_Q       = (const float*)d_in[22];
  const float* b2_Q       = (const float*)d_in[23];
  const float* W1_C       = (const float*)d_in[24];
  const float* b1_C       = (const float*)d_in[25];
  const float* W2_C       = (const float*)d_in[26];
  const float* b2_C       = (const float*)d_in[27];

  char* ws = (char*)d_ws;
  size_t o = 0;
  auto alloc = [&](size_t bytes) -> char* {
    char* p = ws + o;
    o += (bytes + 255) & ~(size_t)255;
    return p;
  };
  // R0 overlay: {xnbQ, xnbC} (phase 1-2) == {hQ, hC} (phase 3)
  char* r0 = alloc(100663296);
  bf16* xnbQ = (bf16*)r0;                     // 33554432 B (NQ x 128)
  bf16* xnbC = (bf16*)(r0 + 33554432);        // 16777216 B (NC x 128)
  bf16* hQ   = (bf16*)r0;                     // 67108864 B (NQ x 256)
  bf16* hC   = (bf16*)(r0 + 67108864);        // 33554432 B (NC x 256)
  bf16* projQ = (bf16*)alloc((size_t)NQn * 128 * 2);
  bf16* projC = (bf16*)alloc((size_t)NCn * 128 * 2);
  bf16* msgQ  = (bf16*)alloc((size_t)NQn * 128 * 2);
  bf16* msgC  = (bf16*)alloc((size_t)NCn * 128 * 2);
  uint2* ebufQC = (uint2*)alloc((size_t)En * 8);
  uint2* ebufCQ = (uint2*)alloc((size_t)En * 8);
  bf16* WresQt = (bf16*)alloc(128 * 128 * 2);
  bf16* WresCt = (bf16*)alloc(128 * 128 * 2);
  bf16* WrelQCt = (bf16*)alloc(128 * 128 * 2);
  bf16* WrelCQt = (bf16*)alloc(128 * 128 * 2);
  bf16* W1Qt = (bf16*)alloc(256 * 256 * 2);
  bf16* W1Ct = (bf16*)alloc(256 * 256 * 2);
  bf16* W2Qt = (bf16*)alloc(128 * 256 * 2);
  bf16* W2Ct = (bf16*)alloc(128 * 256 * 2);
  int* bcnt   = (int*)alloc(1536 * 4);
  int* bbaseQC = (int*)alloc(513 * 4);
  int* bbaseCQ = (int*)alloc(1025 * 4);
  int* gcurQC = (int*)alloc(512 * 4);
  int* gcurCQ = (int*)alloc(1024 * 4);

  float* outQ = (float*)d_out;
  float* outC = (float*)d_out + (size_t)NQn * 128;

  // 1. weight transpose+cast
  wtrans_all<<<dim3(256, 8), 256, 0, stream>>>(
      Wres_Q, WresQt, Wres_C, WresCt, Wrel_QC, WrelQCt, Wrel_CQ, WrelCQt,
      W1_Q, W1Qt, W1_C, W1Ct, W2_Q, W2Qt, W2_C, W2Ct);

  // 2. bucket bases + edge partition (independent of GEMMs)
  bucket_hist<<<384, 256, 0, stream>>>(deg_QC_dst, deg_CQ_dst, bcnt);
  bucket_scan<<<1, 1024, 0, stream>>>(bcnt, bbaseQC, gcurQC, bbaseCQ, gcurCQ);
  bucketA<512><<<En / CHUNK, 256, 0, stream>>>(eQC_src, eQC_dst, gcurQC, ebufQC);
  bucketA<1024><<<En / CHUNK, 256, 0, stream>>>(eCQ_src, eCQ_dst, gcurCQ, ebufCQ);

  // 3. proj = LN(H) @ Wres  (LN fused into A-staging, bf16 out)
  gemm_kernel<ASRC_LN, EPI_BF16, 1><<<dim3(NQn / 128, 1), 256, 0, stream>>>(
      H_Q, nullptr, WresQt, nullptr, nullptr, nullptr, ln_g_Q, ln_b_Q,
      projQ, nullptr, 128, 0, 128);
  gemm_kernel<ASRC_LN, EPI_BF16, 1><<<dim3(NCn / 128, 1), 256, 0, stream>>>(
      H_C, nullptr, WresCt, nullptr, nullptr, nullptr, ln_g_C, ln_b_C,
      projC, nullptr, 128, 0, 128);

  // 4. Xn = (H @ Wrel) * invsqrt(deg_src)  (bf16 out)
  gemm_kernel<ASRC_F32, EPI_RSCL, 1><<<dim3(NQn / 128, 1), 256, 0, stream>>>(
      H_Q, nullptr, WrelQCt, nullptr, deg_QC_src, nullptr, nullptr, nullptr,
      xnbQ, nullptr, 128, 0, 128);
  gemm_kernel<ASRC_F32, EPI_RSCL, 1><<<dim3(NCn / 128, 1), 256, 0, stream>>>(
      H_C, nullptr, WrelCQt, nullptr, deg_CQ_src, nullptr, nullptr, nullptr,
      xnbC, nullptr, 128, 0, 128);

  // 5. fused gather: msgC from xnbQ (QC), msgQ from xnbC (CQ)
  bucket_gather<<<512, 512, 0, stream>>>(ebufQC, bbaseQC, xnbQ, deg_QC_dst,
                                         gate_QC, msgC);
  bucket_gather<<<1024, 512, 0, stream>>>(ebufCQ, bbaseCQ, xnbC, deg_CQ_dst,
                                          gate_CQ, msgQ);

  // 6. MLP layer 1: h = gelu([proj | msg] @ W1 + b1)  (writes over R0 — xnb dead)
  gemm_kernel<ASRC_BF16, EPI_GELU, 2><<<dim3(NQn / 128, 2), 256, 0, stream>>>(
      projQ, msgQ, W1Qt, b1_Q, nullptr, nullptr, nullptr, nullptr,
      hQ, nullptr, 128, 0, 256);
  gemm_kernel<ASRC_BF16, EPI_GELU, 2><<<dim3(NCn / 128, 2), 256, 0, stream>>>(
      projC, msgC, W1Ct, b1_C, nullptr, nullptr, nullptr, nullptr,
      hC, nullptr, 128, 0, 256);

  // 7. MLP layer 2 + residual: out = proj + h @ W2 + b2  (f32 out)
  gemm_kernel<ASRC_BF16, EPI_RES, 2><<<dim3(NQn / 128, 1), 256, 0, stream>>>(
      hQ, hQ, W2Qt, b2_Q, nullptr, projQ, nullptr, nullptr,
      nullptr, outQ, 256, 128, 128);
  gemm_kernel<ASRC_BF16, EPI_RES, 2><<<dim3(NCn / 128, 1), 256, 0, stream>>>(
      hC, hC, W2Ct, b2_C, nullptr, projC, nullptr, nullptr,
      nullptr, outC, 256, 128, 128);
}

// Round 5
// 368.799 us; speedup vs baseline: 4.4175x; 4.4175x over previous
//
#include <hip/hip_runtime.h>
#include <stdint.h>

// Problem sizes (fixed by the reference)
#define NQn 131072
#define NCn 65536
#define En  1048576
// D = 128, HID = 256

typedef __bf16 bf16;
typedef __bf16 bf16x2 __attribute__((ext_vector_type(2)));
typedef __bf16 bf16x4 __attribute__((ext_vector_type(4)));
typedef __bf16 bf16x8 __attribute__((ext_vector_type(8)));
typedef float  f32x4  __attribute__((ext_vector_type(4)));

// ---------------------------------------------------------------------------
// Weight transpose + bf16 cast: Wt[m*K+k] = bf16(W[k*M+m])
// ---------------------------------------------------------------------------
__global__ void wtrans_all(
    const float* __restrict__ w0, bf16* __restrict__ t0,
    const float* __restrict__ w1, bf16* __restrict__ t1,
    const float* __restrict__ w2, bf16* __restrict__ t2,
    const float* __restrict__ w3, bf16* __restrict__ t3,
    const float* __restrict__ w4, bf16* __restrict__ t4,
    const float* __restrict__ w5, bf16* __restrict__ t5,
    const float* __restrict__ w6, bf16* __restrict__ t6,
    const float* __restrict__ w7, bf16* __restrict__ t7) {
  const float* W; bf16* T; int K, M;
  switch (blockIdx.y) {
    case 0: W = w0; T = t0; K = 128; M = 128; break;  // Wres_Q
    case 1: W = w1; T = t1; K = 128; M = 128; break;  // Wres_C
    case 2: W = w2; T = t2; K = 128; M = 128; break;  // Wrel_QC
    case 3: W = w3; T = t3; K = 128; M = 128; break;  // Wrel_CQ
    case 4: W = w4; T = t4; K = 256; M = 256; break;  // W1_Q
    case 5: W = w5; T = t5; K = 256; M = 256; break;  // W1_C
    case 6: W = w6; T = t6; K = 256; M = 128; break;  // W2_Q
    default: W = w7; T = t7; K = 256; M = 128; break; // W2_C
  }
  int t = blockIdx.x * 256 + threadIdx.x;
  if (t >= K * M) return;
  int m = t % M, k = t / M;
  T[m * K + k] = (bf16)W[k * M + m];
}

// ---------------------------------------------------------------------------
// Generic 128x128-tile bf16 MFMA GEMM.
// ASRC: 0 bf16 input; 1 f32 input (cast); 2 f32 input + fused LayerNorm.
// EPI:  0 store bf16; 1 row-scale store bf16; 2 +bias tanh-GELU store bf16;
//       3 +bias +resid store f32.  LDS XOR-swizzled both sides.
// ---------------------------------------------------------------------------
#define ASRC_BF16 0
#define ASRC_F32  1
#define ASRC_LN   2
#define EPI_BF16  0
#define EPI_RSCL  1
#define EPI_GELU  2
#define EPI_RES   3

template <int ASRC, int EPI, int NK>
__global__ __launch_bounds__(256, 2) void gemm_kernel(
    const void* __restrict__ A0, const void* __restrict__ A1,
    const bf16* __restrict__ Bt, const float* __restrict__ bias,
    const float* __restrict__ rowscale, const bf16* __restrict__ resid,
    const float* __restrict__ lng, const float* __restrict__ lnbp,
    bf16* __restrict__ outB, float* __restrict__ outF,
    int ldA, int kOff, int ldOut) {
  __shared__ __align__(16) unsigned char lds[65536];
  const int tid = threadIdx.x;
  const int row0 = blockIdx.x * 128;
  const int col0 = blockIdx.y * 128;
  const int wid = tid >> 6, lane = tid & 63;
  const int wrow = (wid >> 1) * 64, wcol = (wid & 1) * 64;

  f32x4 acc[4][4] = {};

  #pragma unroll
  for (int kc = 0; kc < NK; ++kc) {
    if (kc) __syncthreads();
    const void* ap = (kc == 0) ? A0 : A1;
    const int kofs = kc * kOff;
    if (ASRC == ASRC_F32) {
      const float* Af = (const float*)ap;
      #pragma unroll
      for (int it = 0; it < 16; ++it) {
        int lin = it * 256 + tid;
        int r = lin >> 5;
        int c = (lin & 31) * 4;
        float4 v = *(const float4*)(Af + (size_t)(row0 + r) * ldA + kofs + c);
        bf16x4 w;
        w[0] = (bf16)v.x; w[1] = (bf16)v.y; w[2] = (bf16)v.z; w[3] = (bf16)v.w;
        *(bf16x4*)(lds + r * 256 + ((c * 2) ^ ((r & 7) << 4))) = w;
      }
    } else if (ASRC == ASRC_LN) {
      const float* Af = (const float*)ap;
      #pragma unroll
      for (int it = 0; it < 16; ++it) {
        int lin = it * 256 + tid;
        int r = lin >> 5;
        int c = (lin & 31) * 4;
        float4 v = *(const float4*)(Af + (size_t)(row0 + r) * 128 + c);
        float s = v.x + v.y + v.z + v.w;
        #pragma unroll
        for (int o = 16; o; o >>= 1) s += __shfl_xor(s, o, 64);
        float mean = s * (1.0f / 128.0f);
        float d0 = v.x - mean, d1 = v.y - mean, d2 = v.z - mean, d3 = v.w - mean;
        float q = d0 * d0 + d1 * d1 + d2 * d2 + d3 * d3;
        #pragma unroll
        for (int o = 16; o; o >>= 1) q += __shfl_xor(q, o, 64);
        float rsv = rsqrtf(q * (1.0f / 128.0f) + 1e-5f);
        float4 gg = *(const float4*)(lng + c);
        float4 bb = *(const float4*)(lnbp + c);
        bf16x4 w;
        w[0] = (bf16)(d0 * rsv * gg.x + bb.x);
        w[1] = (bf16)(d1 * rsv * gg.y + bb.y);
        w[2] = (bf16)(d2 * rsv * gg.z + bb.z);
        w[3] = (bf16)(d3 * rsv * gg.w + bb.w);
        *(bf16x4*)(lds + r * 256 + ((c * 2) ^ ((r & 7) << 4))) = w;
      }
    } else {
      const bf16* Ab = (const bf16*)ap;
      #pragma unroll
      for (int it = 0; it < 8; ++it) {
        int lin = it * 256 + tid;
        int r = lin >> 4;
        int cb = (lin & 15) * 16;
        bf16x8 v = *(const bf16x8*)((const char*)Ab +
                    ((size_t)(row0 + r) * ldA + kofs) * 2 + cb);
        *(bf16x8*)(lds + r * 256 + (cb ^ ((r & 7) << 4))) = v;
      }
    }
    #pragma unroll
    for (int it = 0; it < 8; ++it) {
      int lin = it * 256 + tid;
      int r = lin >> 4;
      int cb = (lin & 15) * 16;
      bf16x8 v = *(const bf16x8*)((const char*)Bt +
                  ((size_t)(col0 + r) * (NK * 128) + kc * 128) * 2 + cb);
      *(bf16x8*)(lds + 32768 + r * 256 + (cb ^ ((r & 7) << 4))) = v;
    }
    __syncthreads();
    #pragma unroll
    for (int kk = 0; kk < 4; ++kk) {
      bf16x8 af[4], bfv[4];
      const int kb = kk * 64 + (lane >> 4) * 16;
      #pragma unroll
      for (int fr = 0; fr < 4; ++fr) {
        int ar = wrow + fr * 16 + (lane & 15);
        af[fr] = *(const bf16x8*)(lds + ar * 256 + (kb ^ ((ar & 7) << 4)));
      }
      #pragma unroll
      for (int fc = 0; fc < 4; ++fc) {
        int br = wcol + fc * 16 + (lane & 15);
        bfv[fc] = *(const bf16x8*)(lds + 32768 + br * 256 + (kb ^ ((br & 7) << 4)));
      }
      #pragma unroll
      for (int fr = 0; fr < 4; ++fr)
        #pragma unroll
        for (int fc = 0; fc < 4; ++fc)
          acc[fr][fc] = __builtin_amdgcn_mfma_f32_16x16x32_bf16(
              af[fr], bfv[fc], acc[fr][fc], 0, 0, 0);
    }
  }

  const int rbase = row0 + wrow + (lane >> 4) * 4;
  const int cbase = col0 + wcol + (lane & 15);
  #pragma unroll
  for (int fr = 0; fr < 4; ++fr) {
    float rs[4];
    if (EPI == EPI_RSCL) {
      #pragma unroll
      for (int r = 0; r < 4; ++r) {
        float dv = rowscale[rbase + fr * 16 + r];
        rs[r] = dv > 0.f ? rsqrtf(dv) : 0.f;
      }
    }
    #pragma unroll
    for (int fc = 0; fc < 4; ++fc) {
      const int col = cbase + fc * 16;
      float bv = (EPI == EPI_GELU || EPI == EPI_RES) ? bias[col] : 0.f;
      #pragma unroll
      for (int r = 0; r < 4; ++r) {
        const int row = rbase + fr * 16 + r;
        float x = acc[fr][fc][r];
        if (EPI == EPI_BF16) {
          outB[(size_t)row * ldOut + col] = (bf16)x;
        } else if (EPI == EPI_RSCL) {
          outB[(size_t)row * ldOut + col] = (bf16)(x * rs[r]);
        } else if (EPI == EPI_GELU) {
          x += bv;
          float u2 = 1.5957691216057308f * (x + 0.044715f * x * x * x);
          float e = __expf(u2);
          float th = 1.f - 2.f / (e + 1.f);
          x = 0.5f * x * (1.f + th);
          outB[(size_t)row * ldOut + col] = (bf16)x;
        } else {
          x += bv + (float)resid[(size_t)row * 128 + col];
          outF[(size_t)row * 128 + col] = x;
        }
      }
    }
  }
}

// ---------------------------------------------------------------------------
// Bucket histogram from deg (bucket = 128 dst rows). One wave per bucket.
// bcnt layout: [512 QC][1024 CQ]
// ---------------------------------------------------------------------------
__global__ __launch_bounds__(256) void bucket_hist(
    const float* __restrict__ degQC, const float* __restrict__ degCQ,
    int* __restrict__ bcnt) {
  int w = (blockIdx.x * 256 + threadIdx.x) >> 6;
  int lane = threadIdx.x & 63;
  const float* deg = (w < 512) ? (degQC + (size_t)w * 128)
                               : (degCQ + (size_t)(w - 512) * 128);
  float s = deg[lane] + deg[lane + 64];
  #pragma unroll
  for (int o = 32; o; o >>= 1) s += __shfl_xor(s, o, 64);
  if (lane == 0) bcnt[w] = (int)(s + 0.5f);
}

// Single-block exclusive scan over both bucket-count arrays -> bases + cursors.
__global__ __launch_bounds__(1024) void bucket_scan(
    const int* __restrict__ bcnt,
    int* __restrict__ baseQC, int* __restrict__ gcurQC,
    int* __restrict__ baseCQ, int* __restrict__ gcurCQ) {
  __shared__ int ss[1024];
  const int t = threadIdx.x;
  int v = (t < 512) ? bcnt[t] : 0;
  ss[t] = v;
  __syncthreads();
  for (int o = 1; o < 1024; o <<= 1) {
    int x = (t >= o) ? ss[t - o] : 0;
    __syncthreads();
    ss[t] += x;
    __syncthreads();
  }
  if (t < 512) { int e = ss[t] - v; baseQC[t] = e; gcurQC[t] = e; }
  if (t == 0) baseQC[512] = En;
  __syncthreads();
  int v2 = bcnt[512 + t];
  ss[t] = v2;
  __syncthreads();
  for (int o = 1; o < 1024; o <<= 1) {
    int x = (t >= o) ? ss[t - o] : 0;
    __syncthreads();
    ss[t] += x;
    __syncthreads();
  }
  { int e = ss[t] - v2; baseCQ[t] = e; gcurCQ[t] = e; }
  if (t == 0) baseCQ[1024] = En;
}

// ---------------------------------------------------------------------------
// Pass A: partition (src,dst) pairs into bucket-grouped ebuf (bucket=dst>>7).
// ---------------------------------------------------------------------------
#define CHUNK 4096

template <int NB>
__global__ __launch_bounds__(256) void bucketA(
    const int* __restrict__ esrc, const int* __restrict__ edst,
    int* __restrict__ gcur, uint2* __restrict__ ebuf) {
  __shared__ int lcount[NB], lexcl[NB], lbase[NB], lofs[NB];
  __shared__ int ss[256];
  __shared__ uint2 stage[CHUNK];
  const int t = threadIdx.x;
  for (int b = t; b < NB; b += 256) lcount[b] = 0;
  __syncthreads();
  const int e0 = blockIdx.x * CHUNK;
  uint2 ed[16];
  #pragma unroll
  for (int j = 0; j < 16; ++j) {
    int e = e0 + j * 256 + t;
    ed[j].x = (unsigned)esrc[e];
    ed[j].y = (unsigned)edst[e];
    atomicAdd(&lcount[ed[j].y >> 7], 1);
  }
  __syncthreads();
  constexpr int R = NB / 256;
  int c[R]; int mysum = 0;
  #pragma unroll
  for (int j = 0; j < R; ++j) { c[j] = lcount[t * R + j]; mysum += c[j]; }
  ss[t] = mysum;
  __syncthreads();
  for (int o = 1; o < 256; o <<= 1) {
    int x = (t >= o) ? ss[t - o] : 0;
    __syncthreads();
    ss[t] += x;
    __syncthreads();
  }
  int run = ss[t] - mysum;
  #pragma unroll
  for (int j = 0; j < R; ++j) { lexcl[t * R + j] = run; run += c[j]; }
  __syncthreads();
  for (int b = t; b < NB; b += 256) {
    lbase[b] = atomicAdd(&gcur[b], lcount[b]);
    lofs[b]  = lexcl[b];
  }
  __syncthreads();
  #pragma unroll
  for (int j = 0; j < 16; ++j) {
    int b = ed[j].y >> 7;
    int p = atomicAdd(&lofs[b], 1);
    stage[p] = ed[j];
  }
  __syncthreads();
  for (int i = t; i < CHUNK; i += 256) {
    uint2 v = stage[i];
    int b = v.y >> 7;
    ebuf[lbase[b] + (i - lexcl[b])] = v;
  }
}

// ---------------------------------------------------------------------------
// bucketB2: per 128-dst bucket: local deg-scan -> offs; fill csr window via
// native INT LDS atomics (fast). csr window is contiguous per block (L2-hot).
// ---------------------------------------------------------------------------
__global__ __launch_bounds__(256) void bucketB2(
    const uint2* __restrict__ ebuf, const int* __restrict__ bbase,
    const float* __restrict__ degdst, int* __restrict__ offs,
    int* __restrict__ csr) {
  __shared__ int sdeg[128];
  __shared__ int lcur[128];
  const int b = blockIdx.x;
  const int t = threadIdx.x;
  const int base = bbase[b], end = bbase[b + 1];
  int myv = 0;
  if (t < 128) {
    myv = (int)(degdst[(size_t)b * 128 + t] + 0.5f);
    sdeg[t] = myv;
  }
  __syncthreads();
  for (int o = 1; o < 128; o <<= 1) {
    int x = (t < 128 && t >= o) ? sdeg[t - o] : 0;
    __syncthreads();
    if (t < 128) sdeg[t] += x;
    __syncthreads();
  }
  if (t < 128) {
    int excl = sdeg[t] - myv;
    lcur[t] = excl;
    offs[(size_t)b * 128 + t] = base + excl;
  }
  __syncthreads();
  for (int i = base + t; i < end; i += 256) {
    uint2 v = ebuf[i];
    int p = atomicAdd(&lcur[v.y & 127], 1);
    csr[base + p] = (int)v.x;
  }
}

// ---------------------------------------------------------------------------
// gather2: one wave per dst row, half-wave pairing (each half covers the full
// 128-col row at bf16x4/lane and processes different edges; shfl_xor(32)
// combines). 8 edges in flight per iteration.
// ---------------------------------------------------------------------------
__global__ __launch_bounds__(256) void gather2(
    const bf16* __restrict__ Xn, const int* __restrict__ csr,
    const int* __restrict__ offs, const float* __restrict__ degdst,
    const float* __restrict__ gate, bf16* __restrict__ msg, int ndst) {
  int d = blockIdx.x * 4 + (threadIdx.x >> 6);
  if (d >= ndst) return;
  int lane = threadIdx.x & 63;
  int half = lane >> 5, sl = lane & 31;
  float dv = degdst[d];
  int cnt = (int)(dv + 0.5f);
  int start = offs[d];
  float a0 = 0.f, a1 = 0.f, a2 = 0.f, a3 = 0.f;
  int i = 0;
  for (; i + 8 <= cnt; i += 8) {
    int s0 = csr[start + i + half * 4 + 0];
    int s1 = csr[start + i + half * 4 + 1];
    int s2 = csr[start + i + half * 4 + 2];
    int s3 = csr[start + i + half * 4 + 3];
    bf16x4 v0 = *(const bf16x4*)(Xn + (size_t)s0 * 128 + sl * 4);
    bf16x4 v1 = *(const bf16x4*)(Xn + (size_t)s1 * 128 + sl * 4);
    bf16x4 v2 = *(const bf16x4*)(Xn + (size_t)s2 * 128 + sl * 4);
    bf16x4 v3 = *(const bf16x4*)(Xn + (size_t)s3 * 128 + sl * 4);
    a0 += (float)v0[0] + (float)v1[0] + (float)v2[0] + (float)v3[0];
    a1 += (float)v0[1] + (float)v1[1] + (float)v2[1] + (float)v3[1];
    a2 += (float)v0[2] + (float)v1[2] + (float)v2[2] + (float)v3[2];
    a3 += (float)v0[3] + (float)v1[3] + (float)v2[3] + (float)v3[3];
  }
  for (; i + 2 <= cnt; i += 2) {
    int s0 = csr[start + i + half];
    bf16x4 v0 = *(const bf16x4*)(Xn + (size_t)s0 * 128 + sl * 4);
    a0 += (float)v0[0]; a1 += (float)v0[1];
    a2 += (float)v0[2]; a3 += (float)v0[3];
  }
  if (i < cnt && half == 0) {
    int s0 = csr[start + i];
    bf16x4 v0 = *(const bf16x4*)(Xn + (size_t)s0 * 128 + sl * 4);
    a0 += (float)v0[0]; a1 += (float)v0[1];
    a2 += (float)v0[2]; a3 += (float)v0[3];
  }
  a0 += __shfl_xor(a0, 32, 64);
  a1 += __shfl_xor(a1, 32, 64);
  a2 += __shfl_xor(a2, 32, 64);
  a3 += __shfl_xor(a3, 32, 64);
  if (half == 0) {
    float sc = (dv > 0.f ? rsqrtf(dv) : 0.f) * gate[0];
    bf16x4 r;
    r[0] = (bf16)(a0 * sc); r[1] = (bf16)(a1 * sc);
    r[2] = (bf16)(a2 * sc); r[3] = (bf16)(a3 * sc);
    *(bf16x4*)(msg + (size_t)d * 128 + sl * 4) = r;
  }
}

// ---------------------------------------------------------------------------
extern "C" void kernel_launch(void* const* d_in, const int* in_sizes, int n_in,
                              void* d_out, int out_size, void* d_ws, size_t ws_size,
                              hipStream_t stream) {
  const float* H_Q        = (const float*)d_in[0];
  const float* H_C        = (const float*)d_in[1];
  const int*   eQC_src    = (const int*)d_in[2];
  const int*   eQC_dst    = (const int*)d_in[3];
  const int*   eCQ_src    = (const int*)d_in[4];
  const int*   eCQ_dst    = (const int*)d_in[5];
  const float* deg_QC_src = (const float*)d_in[6];
  const float* deg_QC_dst = (const float*)d_in[7];
  const float* deg_CQ_src = (const float*)d_in[8];
  const float* deg_CQ_dst = (const float*)d_in[9];
  const float* ln_g_Q     = (const float*)d_in[10];
  const float* ln_b_Q     = (const float*)d_in[11];
  const float* Wres_Q     = (const float*)d_in[12];
  const float* ln_g_C     = (const float*)d_in[13];
  const float* ln_b_C     = (const float*)d_in[14];
  const float* Wres_C     = (const float*)d_in[15];
  const float* Wrel_QC    = (const float*)d_in[16];
  const float* Wrel_CQ    = (const float*)d_in[17];
  const float* gate_QC    = (const float*)d_in[18];
  const float* gate_CQ    = (const float*)d_in[19];
  const float* W1_Q       = (const float*)d_in[20];
  const float* b1_Q       = (const float*)d_in[21];
  const float* W2_Q       = (const float*)d_in[22];
  const float* b2_Q       = (const float*)d_in[23];
  const float* W1_C       = (const float*)d_in[24];
  const float* b1_C       = (const float*)d_in[25];
  const float* W2_C       = (const float*)d_in[26];
  const float* b2_C       = (const float*)d_in[27];

  char* ws = (char*)d_ws;
  size_t o = 0;
  auto alloc = [&](size_t bytes) -> char* {
    char* p = ws + o;
    o += (bytes + 255) & ~(size_t)255;
    return p;
  };
  // R0 overlay timeline:
  //   phase A (GEMMs/gather): [xnbQ 32MB][xnbC 16MB][csrQC 8MB][csrCQ 8MB][..]
  //   phase B (MLP):          [hQ 64MB][hC 32MB]
  char* r0 = alloc(100663296);
  bf16* xnbQ = (bf16*)r0;
  bf16* xnbC = (bf16*)(r0 + 33554432);
  int*  csrQC = (int*)(r0 + 50331648);
  int*  csrCQ = (int*)(r0 + 58720256);
  bf16* hQ   = (bf16*)r0;
  bf16* hC   = (bf16*)(r0 + 67108864);
  bf16* projQ = (bf16*)alloc((size_t)NQn * 128 * 2);
  bf16* projC = (bf16*)alloc((size_t)NCn * 128 * 2);
  bf16* msgQ  = (bf16*)alloc((size_t)NQn * 128 * 2);
  bf16* msgC  = (bf16*)alloc((size_t)NCn * 128 * 2);
  uint2* ebufQC = (uint2*)alloc((size_t)En * 8);
  uint2* ebufCQ = (uint2*)alloc((size_t)En * 8);
  bf16* WresQt = (bf16*)alloc(128 * 128 * 2);
  bf16* WresCt = (bf16*)alloc(128 * 128 * 2);
  bf16* WrelQCt = (bf16*)alloc(128 * 128 * 2);
  bf16* WrelCQt = (bf16*)alloc(128 * 128 * 2);
  bf16* W1Qt = (bf16*)alloc(256 * 256 * 2);
  bf16* W1Ct = (bf16*)alloc(256 * 256 * 2);
  bf16* W2Qt = (bf16*)alloc(128 * 256 * 2);
  bf16* W2Ct = (bf16*)alloc(128 * 256 * 2);
  int* bcnt   = (int*)alloc(1536 * 4);
  int* bbaseQC = (int*)alloc(513 * 4);
  int* bbaseCQ = (int*)alloc(1025 * 4);
  int* gcurQC = (int*)alloc(512 * 4);
  int* gcurCQ = (int*)alloc(1024 * 4);
  int* offsQC = (int*)alloc((size_t)NCn * 4);   // per-dst offsets, QC (dst=C)
  int* offsCQ = (int*)alloc((size_t)NQn * 4);   // per-dst offsets, CQ (dst=Q)

  float* outQ = (float*)d_out;
  float* outC = (float*)d_out + (size_t)NQn * 128;

  // 1. weight transpose+cast
  wtrans_all<<<dim3(256, 8), 256, 0, stream>>>(
      Wres_Q, WresQt, Wres_C, WresCt, Wrel_QC, WrelQCt, Wrel_CQ, WrelCQt,
      W1_Q, W1Qt, W1_C, W1Ct, W2_Q, W2Qt, W2_C, W2Ct);

  // 2. bucket bases + edge partition + CSR build
  bucket_hist<<<384, 256, 0, stream>>>(deg_QC_dst, deg_CQ_dst, bcnt);
  bucket_scan<<<1, 1024, 0, stream>>>(bcnt, bbaseQC, gcurQC, bbaseCQ, gcurCQ);
  bucketA<512><<<En / CHUNK, 256, 0, stream>>>(eQC_src, eQC_dst, gcurQC, ebufQC);
  bucketA<1024><<<En / CHUNK, 256, 0, stream>>>(eCQ_src, eCQ_dst, gcurCQ, ebufCQ);
  bucketB2<<<512, 256, 0, stream>>>(ebufQC, bbaseQC, deg_QC_dst, offsQC, csrQC);
  bucketB2<<<1024, 256, 0, stream>>>(ebufCQ, bbaseCQ, deg_CQ_dst, offsCQ, csrCQ);

  // 3. proj = LN(H) @ Wres  (LN fused into A-staging, bf16 out)
  gemm_kernel<ASRC_LN, EPI_BF16, 1><<<dim3(NQn / 128, 1), 256, 0, stream>>>(
      H_Q, nullptr, WresQt, nullptr, nullptr, nullptr, ln_g_Q, ln_b_Q,
      projQ, nullptr, 128, 0, 128);
  gemm_kernel<ASRC_LN, EPI_BF16, 1><<<dim3(NCn / 128, 1), 256, 0, stream>>>(
      H_C, nullptr, WresCt, nullptr, nullptr, nullptr, ln_g_C, ln_b_C,
      projC, nullptr, 128, 0, 128);

  // 4. Xn = (H @ Wrel) * invsqrt(deg_src)  (bf16 out)
  gemm_kernel<ASRC_F32, EPI_RSCL, 1><<<dim3(NQn / 128, 1), 256, 0, stream>>>(
      H_Q, nullptr, WrelQCt, nullptr, deg_QC_src, nullptr, nullptr, nullptr,
      xnbQ, nullptr, 128, 0, 128);
  gemm_kernel<ASRC_F32, EPI_RSCL, 1><<<dim3(NCn / 128, 1), 256, 0, stream>>>(
      H_C, nullptr, WrelCQt, nullptr, deg_CQ_src, nullptr, nullptr, nullptr,
      xnbC, nullptr, 128, 0, 128);

  // 5. gather (scatter-free SpMM): msgC from xnbQ (QC), msgQ from xnbC (CQ)
  gather2<<<NCn / 4, 256, 0, stream>>>(xnbQ, csrQC, offsQC, deg_QC_dst,
                                       gate_QC, msgC, NCn);
  gather2<<<NQn / 4, 256, 0, stream>>>(xnbC, csrCQ, offsCQ, deg_CQ_dst,
                                       gate_CQ, msgQ, NQn);

  // 6. MLP layer 1: h = gelu([proj | msg] @ W1 + b1)  (writes over R0 — xnb/csr dead)
  gemm_kernel<ASRC_BF16, EPI_GELU, 2><<<dim3(NQn / 128, 2), 256, 0, stream>>>(
      projQ, msgQ, W1Qt, b1_Q, nullptr, nullptr, nullptr, nullptr,
      hQ, nullptr, 128, 0, 256);
  gemm_kernel<ASRC_BF16, EPI_GELU, 2><<<dim3(NCn / 128, 2), 256, 0, stream>>>(
      projC, msgC, W1Ct, b1_C, nullptr, nullptr, nullptr, nullptr,
      hC, nullptr, 128, 0, 256);

  // 7. MLP layer 2 + residual: out = proj + h @ W2 + b2  (f32 out)
  gemm_kernel<ASRC_BF16, EPI_RES, 2><<<dim3(NQn / 128, 1), 256, 0, stream>>>(
      hQ, hQ, W2Qt, b2_Q, nullptr, projQ, nullptr, nullptr,
      nullptr, outQ, 256, 128, 128);
  gemm_kernel<ASRC_BF16, EPI_RES, 2><<<dim3(NCn / 128, 1), 256, 0, stream>>>(
      hC, hC, W2Ct, b2_C, nullptr, projC, nullptr, nullptr,
      nullptr, outC, 256, 128, 128);
}